// Round 6
// baseline (251.222 us; speedup 1.0000x reference)
//
#include <hip/hip_runtime.h>
#include <hip/hip_bf16.h>

#define B_ 32
#define H_ 768
#define K_ 65536
#define TOPK 25
#define ENDK 25
#define NBINS 65536

// ws byte offsets
#define OFF_LQT  0           // bf16 tiled lq: 24 chunks * 32 rows * 32 k * 2B = 48 KB
#define OFF_X1   98304
#define OFF_X2   196608
#define OFF_CNT  294912      // u32[16]: [0]=count1, [1]=pos_min
#define OFF_HIST 524288      // u32[64*65536] = 16 MB  (becomes suffix-CDF in-place)

typedef __attribute__((ext_vector_type(8))) short short8v;
typedef __attribute__((ext_vector_type(4))) short short4v;
typedef __attribute__((ext_vector_type(4))) float f32x4;

__device__ inline short f2bf(float f) {
    unsigned u = __builtin_bit_cast(unsigned, f);
    unsigned r = (u + 0x7FFFu + ((u >> 16) & 1u)) >> 16;   // RNE
    return (short)r;
}

// Zero the 16 MB hist + cnt. Grid-stride float4: 2048 blocks x 256 thr.
__global__ __launch_bounds__(256) void k_zero(float4* __restrict__ hist4,
                                              unsigned* __restrict__ cnt) {
    const float4 z = {0.f, 0.f, 0.f, 0.f};
    int i = blockIdx.x * 256 + threadIdx.x;
    hist4[i] = z;
    hist4[i + 524288] = z;
    if (blockIdx.x == 0 && threadIdx.x < 16) cnt[threadIdx.x] = 0u;
}

// x_out[b][j] = (tanh?) ( sum_e in[b][e]*w[j][e] + bias[j] ); 4 waves/block, wave per j
__global__ __launch_bounds__(256) void k_dense(const float* __restrict__ in, const float* __restrict__ w,
                        const float* __restrict__ bias, float* __restrict__ out,
                        int apply_tanh) {
    int j = blockIdx.x * 4 + (threadIdx.x >> 6);
    int lane = threadIdx.x & 63;
    float acc[B_];
#pragma unroll
    for (int b = 0; b < B_; ++b) acc[b] = 0.f;
#pragma unroll
    for (int c = 0; c < 12; ++c) {
        float wv = w[j * H_ + lane + 64 * c];
#pragma unroll
        for (int b = 0; b < B_; ++b) acc[b] += in[b * H_ + lane + 64 * c] * wv;
    }
    float bj = bias[j];
#pragma unroll
    for (int b = 0; b < B_; ++b) {
        float v = acc[b];
#pragma unroll
        for (int off = 32; off > 0; off >>= 1) v += __shfl_xor(v, off, 64);
        if (lane == b) {
            float r = v + bj;
            out[b * H_ + j] = apply_tanh ? tanhf(r) : r;
        }
    }
}

// Normalize rows of x2 and emit bf16 A-fragments tiled as lqt[ch][row][kk]:
// element (b, k) -> lqt[(k>>5)*1024 + b*32 + (k&31)]
__global__ void k_norm(const float* __restrict__ x2, short* __restrict__ lqt) {
    int b = blockIdx.x, lane = threadIdx.x;
    float v[12];
    float ss = 0.f;
#pragma unroll
    for (int c = 0; c < 12; ++c) {
        v[c] = x2[b * H_ + lane + 64 * c];
        ss += v[c] * v[c];
    }
#pragma unroll
    for (int off = 32; off > 0; off >>= 1) ss += __shfl_xor(ss, off, 64);
    float rn = 1.0f / sqrtf(ss);
#pragma unroll
    for (int c = 0; c < 12; ++c) {
        int k = lane + 64 * c;
        lqt[(k >> 5) * 1024 + b * 32 + (k & 31)] = f2bf(v[c] * rn);
    }
}

// MFMA GEMM (32 x 65536 x 768, bf16/fp32-acc) + histogram binning.
// Block = 4 waves, owns 64 fq rows. fq staged through swizzled LDS in 128-col
// steps (contiguous 512B-run loads, double-buffered, reg-prefetched).
// Wave w computes C[0..32)[w*16..w*16+16) over full H.
__global__ __launch_bounds__(256) void k_gemm_hist(
    const float* __restrict__ fq, const short* __restrict__ lqt,
    const int* __restrict__ labels, const int* __restrict__ lblq,
    unsigned* __restrict__ hist) {
    __shared__ short lds[2][64 * 128];    // bf16, XOR-swizzled rows of 256 B
    const int t = threadIdx.x;
    const int l = t & 63;
    const int w = t >> 6;                 // wave 0..3
    const int n = l & 15, o = l >> 4;     // MFMA lane coords
    const int kbase = blockIdx.x * 64;

    // staging map: load j (0..7): row = j*8 + (t>>5), f4-col = t&31
    const int srow = t >> 5;              // + j*8
    const int sc4 = t & 31;

    f32x4 acc0 = {0.f, 0.f, 0.f, 0.f};
    f32x4 acc1 = {0.f, 0.f, 0.f, 0.f};

    float4 pf[8];
#define STAGE_LOAD(HB) \
    _Pragma("unroll") \
    for (int j = 0; j < 8; ++j) \
        pf[j] = *(const float4*)(fq + (size_t)(kbase + j * 8 + srow) * H_ + (HB) + sc4 * 4);

#define STAGE_WRITE(BUF) \
    _Pragma("unroll") \
    for (int j = 0; j < 8; ++j) { \
        int row = j * 8 + srow; \
        short4v bv; \
        bv[0] = f2bf(pf[j].x); bv[1] = f2bf(pf[j].y); \
        bv[2] = f2bf(pf[j].z); bv[3] = f2bf(pf[j].w); \
        int byte = row * 256 + ((sc4 * 8) ^ ((row & 15) << 4)); \
        *(short4v*)((char*)lds[BUF] + byte) = bv; \
    }

    STAGE_LOAD(0)
    STAGE_WRITE(0)
    __syncthreads();

    const int rowb = (w * 16 + n) * 256;      // my B-frag row base (byte)
    const int swz = n << 4;

    for (int s = 0; s < 6; ++s) {
        const int cur = s & 1;
        if (s < 5) STAGE_LOAD((s + 1) * 128)
#pragma unroll
        for (int ch = 0; ch < 4; ++ch) {
            const int C = s * 4 + ch;
            short8v bfrag = *(const short8v*)((const char*)lds[cur] +
                             rowb + (((ch * 64 + o * 16)) ^ swz));
            short8v a0 = *(const short8v*)(lqt + C * 1024 + n * 32 + o * 8);
            short8v a1 = *(const short8v*)(lqt + C * 1024 + 512 + n * 32 + o * 8);
            acc0 = __builtin_amdgcn_mfma_f32_16x16x32_bf16(a0, bfrag, acc0, 0, 0, 0);
            acc1 = __builtin_amdgcn_mfma_f32_16x16x32_bf16(a1, bfrag, acc1, 0, 0, 0);
        }
        if (s < 5) STAGE_WRITE(cur ^ 1)
        __syncthreads();
    }
#undef STAGE_LOAD
#undef STAGE_WRITE

    // D layout: col = lane&15 (fq row n), row m = (lane>>4)*4 + reg (b index)
    const int myk = kbase + w * 16 + n;
    const int myql = lblq[myk];
#define EMIT(ACC, MT) \
    _Pragma("unroll") \
    for (int i = 0; i < 4; ++i) { \
        int m = (MT) * 16 + o * 4 + i; \
        int g = (labels[m] == myql) ? 1 : 0; \
        float v = ACC[i]; \
        int bin = (int)floorf((v + 0.5f) * 65536.0f); \
        bin = bin < 0 ? 0 : (bin > 65535 ? 65535 : bin); \
        atomicAdd(&hist[(unsigned)(((m << 1) | g) << 16) + (unsigned)bin], 1u); \
    }
    EMIT(acc0, 0)
    EMIT(acc1, 1)
#undef EMIT
}

__global__ void k_count1(const int* __restrict__ lblq, unsigned* __restrict__ cnt) {
    int idx = blockIdx.x * blockDim.x + threadIdx.x;  // 16384 threads
    unsigned local = 0;
    for (int k = idx; k < K_; k += 16384) local += (unsigned)lblq[k];
#pragma unroll
    for (int off = 32; off > 0; off >>= 1) local += (unsigned)__shfl_xor((int)local, off, 64);
    if ((threadIdx.x & 63) == 0) atomicAdd(cnt, local);
}

__global__ void k_posmin(const int* __restrict__ labels, const unsigned* __restrict__ cnt,
                         unsigned* __restrict__ posmin) {
    int lane = threadIdx.x;
    unsigned c1 = *cnt;
    unsigned cp = 0x7fffffffu;
    if (lane < B_) cp = (labels[lane] == 1) ? c1 : ((unsigned)K_ - c1);
#pragma unroll
    for (int off = 32; off > 0; off >>= 1) {
        unsigned o = (unsigned)__shfl_xor((int)cp, off, 64);
        cp = o < cp ? o : cp;
    }
    if (lane == 0) *posmin = cp;
}

// Convert hist in-place to suffix-CDF: S[i] = # elements in bins >= i.
__global__ __launch_bounds__(1024) void k_scan(unsigned* __restrict__ hist) {
    int seg = blockIdx.x;
    unsigned* h = hist + (size_t)seg * NBINS + threadIdx.x * 64;
    int lane = threadIdx.x & 63, wid = threadIdx.x >> 6;
    unsigned s = 0;
    for (int i = 0; i < 64; ++i) s += h[i];
    unsigned v = s;
#pragma unroll
    for (int off = 1; off < 64; off <<= 1) {
        unsigned u = (unsigned)__shfl_up((int)v, off, 64);
        if (lane >= off) v += u;
    }
    __shared__ unsigned wsum[16];
    if (lane == 63) wsum[wid] = v;
    __syncthreads();
    unsigned wexcl = 0, tot = 0;
#pragma unroll
    for (int i = 0; i < 16; ++i) {
        unsigned x = wsum[i];
        if (i < wid) wexcl += x;
        tot += x;
    }
    unsigned run = wexcl + v - s;   // elements in bins below mine
    for (int i = 0; i < 64; ++i) {
        unsigned c = h[i];
        h[i] = tot - run;           // S[i]
        run += c;
    }
}

// rank p (descending) -> bin: largest i with S[i] > p
__device__ inline int bsearch_bin(const unsigned* __restrict__ S, unsigned p) {
    int lo = 0, hi = NBINS;
#pragma unroll
    for (int it = 0; it < 17; ++it) {
        if (hi - lo > 1) {
            int mid = (lo + hi) >> 1;
            bool gt = S[mid] > p;
            lo = gt ? mid : lo;
            hi = gt ? hi : mid;
        }
    }
    return lo;
}

__device__ inline float bin_val(int bin) {
    return ((float)bin + 0.5f) * (1.0f / 65536.0f) - 0.5f;
}

// Output writer: rank-search the CDF, broadcast to 50 repeat rows (coalesced).
__global__ __launch_bounds__(1024) void k_out(const unsigned* __restrict__ S,
                                              const unsigned* __restrict__ posmin,
                                              float* __restrict__ out, int W) {
    int b = blockIdx.x;       // 0..31
    int cb = blockIdx.y;
    const float invT = 14.285714285714286f;  // 1/0.07
    if (cb == 0 && threadIdx.x < (TOPK + ENDK)) {
        int pm = (int)*posmin;
        int j = threadIdx.x;
        int p = (j < TOPK) ? j : (pm - ENDK + (j - TOPK));
        const unsigned* Sp = S + (size_t)(b * 2 + 1) * NBINS;
        int bin = bsearch_bin(Sp, (unsigned)p);
        out[(size_t)(b * (TOPK + ENDK) + j) * W] = bin_val(bin) * invT;
    }
    int c = 1 + cb * 1024 + threadIdx.x;
    if (c < W) {
        const unsigned* Sn = S + (size_t)(b * 2) * NBINS;
        int bin = bsearch_bin(Sn, (unsigned)(c - 1));
        float v = bin_val(bin) * invT;
        float* o = out + (size_t)b * (TOPK + ENDK) * W + c;
#pragma unroll
        for (int r = 0; r < TOPK + ENDK; ++r) o[(size_t)r * W] = v;
    }
}

extern "C" void kernel_launch(void* const* d_in, const int* in_sizes, int n_in,
                              void* d_out, int out_size, void* d_ws, size_t ws_size,
                              hipStream_t stream) {
    const float* q   = (const float*)d_in[0];
    const float* dw  = (const float*)d_in[1];
    const float* db  = (const float*)d_in[2];
    const float* ow  = (const float*)d_in[3];
    const float* ob  = (const float*)d_in[4];
    const int* labels = (const int*)d_in[5];
    const int* lblq   = (const int*)d_in[6];
    const float* fq   = (const float*)d_in[7];

    char* ws = (char*)d_ws;
    short* lqt = (short*)(ws + OFF_LQT);
    float* x1 = (float*)(ws + OFF_X1);
    float* x2 = (float*)(ws + OFF_X2);
    unsigned* cnt  = (unsigned*)(ws + OFF_CNT);
    unsigned* hist = (unsigned*)(ws + OFF_HIST);

    int W = out_size / (B_ * (TOPK + ENDK));  // 1 + neg_min

    k_zero<<<2048, 256, 0, stream>>>((float4*)hist, cnt);
    k_dense<<<H_ / 4, 256, 0, stream>>>(q, dw, db, x1, 1);
    k_dense<<<H_ / 4, 256, 0, stream>>>(x1, ow, ob, x2, 0);
    k_norm<<<B_, 64, 0, stream>>>(x2, lqt);
    k_gemm_hist<<<K_ / 64, 256, 0, stream>>>(fq, lqt, labels, lblq, hist);
    k_count1<<<64, 256, 0, stream>>>(lblq, cnt);
    k_posmin<<<1, 64, 0, stream>>>(labels, cnt, cnt + 1);
    k_scan<<<64, 1024, 0, stream>>>(hist);

    dim3 gb(B_, (unsigned)((W - 1 + 1023) / 1024));
    k_out<<<gb, 1024, 0, stream>>>(hist, cnt + 1, (float*)d_out, W);
}

// Round 7
// 212.659 us; speedup vs baseline: 1.1813x; 1.1813x over previous
//
#include <hip/hip_runtime.h>
#include <hip/hip_bf16.h>

#define B_ 32
#define H_ 768
#define K_ 65536
#define TOPK 25
#define ENDK 25
#define NBINS 65536
#define WLO 28672            // histogram LDS window: [WLO, WLO+8192)
#define WSZ 8192

// ws byte offsets
#define OFF_LQT  0           // bf16 tiled lq: 24 chunks * 32 rows * 32 k * 2B = 48 KB
#define OFF_X1   98304
#define OFF_X2   196608
#define OFF_CNT  294912      // u32[16]: [0]=count1, [1]=pos_min
#define OFF_HIST 524288      // u32[64*65536] = 16 MB  (becomes suffix-CDF in-place)
#define OFF_BIDX 17825792    // u16[32*65536] = 4 MB bin indices

typedef __attribute__((ext_vector_type(8))) short short8v;
typedef __attribute__((ext_vector_type(4))) float f32x4;

__device__ inline short f2bf(float f) {
    unsigned u = __builtin_bit_cast(unsigned, f);
    unsigned r = (u + 0x7FFFu + ((u >> 16) & 1u)) >> 16;   // RNE
    return (short)r;
}

// Zero the 16 MB hist + cnt. Grid-stride float4: 2048 blocks x 256 thr.
__global__ __launch_bounds__(256) void k_zero(float4* __restrict__ hist4,
                                              unsigned* __restrict__ cnt) {
    const float4 z = {0.f, 0.f, 0.f, 0.f};
    int i = blockIdx.x * 256 + threadIdx.x;
    hist4[i] = z;
    hist4[i + 524288] = z;
    if (blockIdx.x == 0 && threadIdx.x < 16) cnt[threadIdx.x] = 0u;
}

// x_out[b][j] = (tanh?) ( sum_e in[b][e]*w[j][e] + bias[j] ); 4 waves/block, wave per j
__global__ __launch_bounds__(256) void k_dense(const float* __restrict__ in, const float* __restrict__ w,
                        const float* __restrict__ bias, float* __restrict__ out,
                        int apply_tanh) {
    int j = blockIdx.x * 4 + (threadIdx.x >> 6);
    int lane = threadIdx.x & 63;
    float acc[B_];
#pragma unroll
    for (int b = 0; b < B_; ++b) acc[b] = 0.f;
#pragma unroll
    for (int c = 0; c < 12; ++c) {
        float wv = w[j * H_ + lane + 64 * c];
#pragma unroll
        for (int b = 0; b < B_; ++b) acc[b] += in[b * H_ + lane + 64 * c] * wv;
    }
    float bj = bias[j];
#pragma unroll
    for (int b = 0; b < B_; ++b) {
        float v = acc[b];
#pragma unroll
        for (int off = 32; off > 0; off >>= 1) v += __shfl_xor(v, off, 64);
        if (lane == b) {
            float r = v + bj;
            out[b * H_ + j] = apply_tanh ? tanhf(r) : r;
        }
    }
}

// Normalize rows of x2 and emit bf16 A-fragments tiled as lqt[ch][row][kk]:
// element (b, k) -> lqt[(k>>5)*1024 + b*32 + (k&31)]
__global__ void k_norm(const float* __restrict__ x2, short* __restrict__ lqt) {
    int b = blockIdx.x, lane = threadIdx.x;
    float v[12];
    float ss = 0.f;
#pragma unroll
    for (int c = 0; c < 12; ++c) {
        v[c] = x2[b * H_ + lane + 64 * c];
        ss += v[c] * v[c];
    }
#pragma unroll
    for (int off = 32; off > 0; off >>= 1) ss += __shfl_xor(ss, off, 64);
    float rn = 1.0f / sqrtf(ss);
#pragma unroll
    for (int c = 0; c < 12; ++c) {
        int k = lane + 64 * c;
        lqt[(k >> 5) * 1024 + b * 32 + (k & 31)] = f2bf(v[c] * rn);
    }
}

// MFMA GEMM (32 x 65536 x 768, bf16 in / fp32 acc) -> u16 bin indices.
// H-reduction split across wave pairs (12 chunks each); combine via LDS.
// 2048 blocks x 4 waves = 8192 waves. NO global atomics.
__global__ __launch_bounds__(256) void k_gemm_bin(
    const float* __restrict__ fq, const short* __restrict__ lqt,
    unsigned short* __restrict__ binidx) {
    __shared__ float xch[2][64][8];
    const int l = threadIdx.x & 63;
    const int w = threadIdx.x >> 6;       // 0..3
    const int pair = w >> 1;              // 0..1 : which 16-row fq tile
    const int half = w & 1;               // 0..1 : which H half
    const int nb = (blockIdx.x * 2 + pair) * 16;
    const int r = l & 15, o = l >> 4;

    const float* fbase = fq + (size_t)(nb + r) * H_ + half * 384 + o * 8;
    const short* abase = lqt + half * 12 * 1024 + r * 32 + o * 8;

    f32x4 acc0 = {0.f, 0.f, 0.f, 0.f};
    f32x4 acc1 = {0.f, 0.f, 0.f, 0.f};

#pragma unroll 4
    for (int ch = 0; ch < 12; ++ch) {
        float4 b0 = *(const float4*)(fbase + ch * 32);
        float4 b1 = *(const float4*)(fbase + ch * 32 + 4);
        short8v bf;
        bf[0] = f2bf(b0.x); bf[1] = f2bf(b0.y); bf[2] = f2bf(b0.z); bf[3] = f2bf(b0.w);
        bf[4] = f2bf(b1.x); bf[5] = f2bf(b1.y); bf[6] = f2bf(b1.z); bf[7] = f2bf(b1.w);
        short8v a0 = *(const short8v*)(abase + ch * 1024);
        short8v a1 = *(const short8v*)(abase + ch * 1024 + 512);
        acc0 = __builtin_amdgcn_mfma_f32_16x16x32_bf16(a0, bf, acc0, 0, 0, 0);
        acc1 = __builtin_amdgcn_mfma_f32_16x16x32_bf16(a1, bf, acc1, 0, 0, 0);
    }

    if (half == 1) {
#pragma unroll
        for (int i = 0; i < 4; ++i) {
            xch[pair][l][i] = acc0[i];
            xch[pair][l][i + 4] = acc1[i];
        }
    }
    __syncthreads();
    if (half == 0) {
        const int myk = nb + r;
#pragma unroll
        for (int i = 0; i < 4; ++i) {
            acc0[i] += xch[pair][l][i];
            acc1[i] += xch[pair][l][i + 4];
        }
        // D layout: col = lane&15 (fq row k), row m = (lane>>4)*4 + reg (b index)
#define EMIT(ACC, MT) \
        _Pragma("unroll") \
        for (int i = 0; i < 4; ++i) { \
            int m = (MT) * 16 + o * 4 + i; \
            float v = ACC[i]; \
            int bin = (int)floorf((v + 0.5f) * 65536.0f); \
            bin = bin < 0 ? 0 : (bin > 65535 ? 65535 : bin); \
            binidx[(size_t)m * K_ + myk] = (unsigned short)bin; \
        }
        EMIT(acc0, 0)
        EMIT(acc1, 1)
#undef EMIT
    }
}

// Privatized histogram: one block per b-row; LDS u32[2][8192] window;
// plain-store dump (exclusive ownership), rare outliers via global atomic.
__global__ __launch_bounds__(1024) void k_hist(
    const unsigned short* __restrict__ binidx,
    const int* __restrict__ labels, const int* __restrict__ lblq,
    unsigned* __restrict__ hist) {
    __shared__ unsigned lh[2 * WSZ];
    const int b = blockIdx.x, t = threadIdx.x;
    for (int j = t; j < 2 * WSZ; j += 1024) lh[j] = 0u;
    __syncthreads();
    const int mylab = labels[b];
    const unsigned short* row = binidx + (size_t)b * K_;
#pragma unroll 4
    for (int i = 0; i < 64; ++i) {
        int k = i * 1024 + t;
        unsigned bin = row[k];
        int g = (lblq[k] == mylab) ? 1 : 0;
        int wv = (int)bin - WLO;
        if ((unsigned)wv < (unsigned)WSZ) atomicAdd(&lh[g * WSZ + wv], 1u);
        else atomicAdd(&hist[(unsigned)(((b << 1) | g) << 16) + bin], 1u);
    }
    __syncthreads();
    unsigned* h0 = hist + ((size_t)(b * 2) << 16) + WLO;
    unsigned* h1 = hist + ((size_t)(b * 2 + 1) << 16) + WLO;
    for (int j = t; j < WSZ; j += 1024) {
        h0[j] = lh[j];
        h1[j] = lh[WSZ + j];
    }
}

__global__ void k_count1(const int* __restrict__ lblq, unsigned* __restrict__ cnt) {
    int idx = blockIdx.x * blockDim.x + threadIdx.x;  // 16384 threads
    unsigned local = 0;
    for (int k = idx; k < K_; k += 16384) local += (unsigned)lblq[k];
#pragma unroll
    for (int off = 32; off > 0; off >>= 1) local += (unsigned)__shfl_xor((int)local, off, 64);
    if ((threadIdx.x & 63) == 0) atomicAdd(cnt, local);
}

__global__ void k_posmin(const int* __restrict__ labels, const unsigned* __restrict__ cnt,
                         unsigned* __restrict__ posmin) {
    int lane = threadIdx.x;
    unsigned c1 = *cnt;
    unsigned cp = 0x7fffffffu;
    if (lane < B_) cp = (labels[lane] == 1) ? c1 : ((unsigned)K_ - c1);
#pragma unroll
    for (int off = 32; off > 0; off >>= 1) {
        unsigned o = (unsigned)__shfl_xor((int)cp, off, 64);
        cp = o < cp ? o : cp;
    }
    if (lane == 0) *posmin = cp;
}

// Convert hist in-place to suffix-CDF: S[i] = # elements in bins >= i.
__global__ __launch_bounds__(1024) void k_scan(unsigned* __restrict__ hist) {
    int seg = blockIdx.x;
    unsigned* h = hist + (size_t)seg * NBINS + threadIdx.x * 64;
    int lane = threadIdx.x & 63, wid = threadIdx.x >> 6;
    unsigned s = 0;
    for (int i = 0; i < 64; ++i) s += h[i];
    unsigned v = s;
#pragma unroll
    for (int off = 1; off < 64; off <<= 1) {
        unsigned u = (unsigned)__shfl_up((int)v, off, 64);
        if (lane >= off) v += u;
    }
    __shared__ unsigned wsum[16];
    if (lane == 63) wsum[wid] = v;
    __syncthreads();
    unsigned wexcl = 0, tot = 0;
#pragma unroll
    for (int i = 0; i < 16; ++i) {
        unsigned x = wsum[i];
        if (i < wid) wexcl += x;
        tot += x;
    }
    unsigned run = wexcl + v - s;   // elements in bins below mine
    for (int i = 0; i < 64; ++i) {
        unsigned c = h[i];
        h[i] = tot - run;           // S[i]
        run += c;
    }
}

// rank p (descending) -> bin: largest i with S[i] > p
__device__ inline int bsearch_bin(const unsigned* __restrict__ S, unsigned p) {
    int lo = 0, hi = NBINS;
#pragma unroll
    for (int it = 0; it < 17; ++it) {
        if (hi - lo > 1) {
            int mid = (lo + hi) >> 1;
            bool gt = S[mid] > p;
            lo = gt ? mid : lo;
            hi = gt ? hi : mid;
        }
    }
    return lo;
}

__device__ inline float bin_val(int bin) {
    return ((float)bin + 0.5f) * (1.0f / 65536.0f) - 0.5f;
}

// Output writer: rank-search the CDF, broadcast to 50 repeat rows (coalesced).
__global__ __launch_bounds__(1024) void k_out(const unsigned* __restrict__ S,
                                              const unsigned* __restrict__ posmin,
                                              float* __restrict__ out, int W) {
    int b = blockIdx.x;       // 0..31
    int cb = blockIdx.y;
    const float invT = 14.285714285714286f;  // 1/0.07
    if (cb == 0 && threadIdx.x < (TOPK + ENDK)) {
        int pm = (int)*posmin;
        int j = threadIdx.x;
        int p = (j < TOPK) ? j : (pm - ENDK + (j - TOPK));
        const unsigned* Sp = S + (size_t)(b * 2 + 1) * NBINS;
        int bin = bsearch_bin(Sp, (unsigned)p);
        out[(size_t)(b * (TOPK + ENDK) + j) * W] = bin_val(bin) * invT;
    }
    int c = 1 + cb * 1024 + threadIdx.x;
    if (c < W) {
        const unsigned* Sn = S + (size_t)(b * 2) * NBINS;
        int bin = bsearch_bin(Sn, (unsigned)(c - 1));
        float v = bin_val(bin) * invT;
        float* o = out + (size_t)b * (TOPK + ENDK) * W + c;
#pragma unroll
        for (int r = 0; r < TOPK + ENDK; ++r) o[(size_t)r * W] = v;
    }
}

extern "C" void kernel_launch(void* const* d_in, const int* in_sizes, int n_in,
                              void* d_out, int out_size, void* d_ws, size_t ws_size,
                              hipStream_t stream) {
    const float* q   = (const float*)d_in[0];
    const float* dw  = (const float*)d_in[1];
    const float* db  = (const float*)d_in[2];
    const float* ow  = (const float*)d_in[3];
    const float* ob  = (const float*)d_in[4];
    const int* labels = (const int*)d_in[5];
    const int* lblq   = (const int*)d_in[6];
    const float* fq   = (const float*)d_in[7];

    char* ws = (char*)d_ws;
    short* lqt = (short*)(ws + OFF_LQT);
    float* x1 = (float*)(ws + OFF_X1);
    float* x2 = (float*)(ws + OFF_X2);
    unsigned* cnt  = (unsigned*)(ws + OFF_CNT);
    unsigned* hist = (unsigned*)(ws + OFF_HIST);
    unsigned short* binidx = (unsigned short*)(ws + OFF_BIDX);

    int W = out_size / (B_ * (TOPK + ENDK));  // 1 + neg_min

    k_zero<<<2048, 256, 0, stream>>>((float4*)hist, cnt);
    k_dense<<<H_ / 4, 256, 0, stream>>>(q, dw, db, x1, 1);
    k_dense<<<H_ / 4, 256, 0, stream>>>(x1, ow, ob, x2, 0);
    k_norm<<<B_, 64, 0, stream>>>(x2, lqt);
    k_gemm_bin<<<K_ / 32, 256, 0, stream>>>(fq, lqt, binidx);
    k_count1<<<64, 256, 0, stream>>>(lblq, cnt);
    k_posmin<<<1, 64, 0, stream>>>(labels, cnt, cnt + 1);
    k_hist<<<B_, 1024, 0, stream>>>(binidx, labels, lblq, hist);
    k_scan<<<64, 1024, 0, stream>>>(hist);

    dim3 gb(B_, (unsigned)((W - 1 + 1023) / 1024));
    k_out<<<gb, 1024, 0, stream>>>(hist, cnt + 1, (float*)d_out, W);
}